// Round 5
// baseline (197.034 us; speedup 1.0000x reference)
//
#include <hip/hip_runtime.h>
#include <math.h>

// Sampler: temperature 0.8, top-k (k=50 input), top-p 0.9, inverse-CDF
// multinomial. B=128 rows, V=128000, fp32 logits -> int32 ids.
//
// R5: FUSED single kernel (grid = B x SLICES, 256 thr), last-block-done:
//  - scan phase: each block streams its slice (8 float4 in flight), stages
//    candidates (y >= 11.2 i.e. x >= 14) via LDS atomics, writes its PRIVATE
//    global segment + count. No cross-block atomics on the hot path.
//  - completion: __threadfence() (agent release) + atomicAdd(done[row],1);
//    the arriving block with old == SLICES-1 becomes the row's selector
//    (rocPRIM last-block pattern; acquire fence before reading segments).
//  - select phase (winner block only, overlaps other rows' scans):
//    gather 16 segments, two-tier filter (if #{x>=16} >= k sort only those,
//    ~88 elems; provably contains top-k + kth ties), exact rank sort by
//    (x desc, idx asc) == jnp.argsort(-x) stability, then the serial fp32
//    softmax / top-p / inverse-CDF tail (byte-identical to the absmax-0
//    R1-R4 code). Exact fallback: kth via binary search on float key bits.
//  - done[] counters zeroed by a 512 B hipMemsetAsync (graph-capturable).
// LDS: 2 KB staging + 20 KB aliased select arrays = 22 KB -> 7 blocks/CU.

#define SLICES 16
#define SEGCAP 256
#define MSORT  1024

__device__ __forceinline__ unsigned fkey(float y) {
    unsigned b = __float_as_uint(y);
    return (b & 0x80000000u) ? ~b : (b | 0x80000000u);  // y asc -> key asc
}

__global__ __launch_bounds__(256)
void fused_sampler_kernel(const float* __restrict__ logits,
                          const float* __restrict__ uvec,
                          const int* __restrict__ topk_p,
                          int* __restrict__ done,
                          int* __restrict__ scnt,
                          float* __restrict__ cy, int* __restrict__ ci,
                          int* __restrict__ out, int V)
{
    constexpr float YTH  = 11.2f;   // x = 14.0 candidate threshold
    constexpr float TEMP = 0.8f;
    constexpr float TOPP = 0.9f;
    constexpr float XTH2 = 16.0f;   // two-tier threshold in x-space

    __shared__ float lcy[SEGCAP];   // scan staging
    __shared__ int   lci[SEGCAP];
    __shared__ int   lcnt, winner_sh;
    // select-phase arrays (aliased across phases):
    __shared__ float gv[MSORT];     // gather x      -> later sorted ssv
    __shared__ int   gi[MSORT];     // gather idx    -> later sorted ssi
    __shared__ float cv[MSORT];     // compacted x   -> later se = exp(x-max)
    __shared__ int   cidx[MSORT];   // compacted idx -> later sidx2 (vocab order)
    __shared__ float sq[MSORT];     // final probs, vocab order
    __shared__ int   segc[SLICES], segoff[SLICES + 1];
    __shared__ int   bad_sh, hi_cnt, cpos, scount, cnt_sh, L_sh, M_sh;
    __shared__ float sum2_sh;

    const int tid = threadIdx.x;
    const int row = blockIdx.x / SLICES;
    const int sl  = blockIdx.x % SLICES;
    if (tid == 0) lcnt = 0;
    __syncthreads();

    const float* rowp = logits + (size_t)row * (size_t)V;
    const float4* rp4 = (const float4*)rowp;
    const int n4  = V >> 2;
    const int per = (n4 + SLICES - 1) / SLICES;
    const int s0  = sl * per;
    const int s1  = min(s0 + per, n4);

    // ---------------- scan phase: 8 float4 loads in flight ----------------
    for (int cb = s0; cb < s1; cb += 8 * 256) {
        float4 vals[8];
        const int base = cb + tid;
#pragma unroll
        for (int j = 0; j < 8; ++j) {
            int i = base + j * 256;
            vals[j] = (i < s1) ? rp4[i]
                               : make_float4(-1e30f, -1e30f, -1e30f, -1e30f);
        }
#pragma unroll
        for (int j = 0; j < 8; ++j) {
            int i = base + j * 256;
            float ys[4] = {vals[j].x, vals[j].y, vals[j].z, vals[j].w};
#pragma unroll
            for (int c = 0; c < 4; ++c) {
                if (ys[c] >= YTH) {
                    int p = atomicAdd(&lcnt, 1);      // LDS atomic
                    if (p < SEGCAP) { lcy[p] = ys[c]; lci[p] = i * 4 + c; }
                }
            }
        }
    }
    if (sl == SLICES - 1) {  // scalar tail if V % 4 != 0
        for (int i = (n4 << 2) + tid; i < V; i += 256) {
            float y = rowp[i];
            if (y >= YTH) {
                int p = atomicAdd(&lcnt, 1);
                if (p < SEGCAP) { lcy[p] = y; lci[p] = i; }
            }
        }
    }
    __syncthreads();

    const int cnt = lcnt;
    {
        float* cyr = cy + ((size_t)row * SLICES + sl) * SEGCAP;
        int*   cir = ci + ((size_t)row * SLICES + sl) * SEGCAP;
        for (int p = tid; p < min(cnt, SEGCAP); p += 256) {
            cyr[p] = lcy[p];
            cir[p] = lci[p];
        }
        if (tid == 0) scnt[row * SLICES + sl] = cnt;  // >SEGCAP => overflow flag
    }
    __syncthreads();   // all segment stores complete (vmcnt drained) before fence
    if (tid == 0) {
        __threadfence();                               // agent-scope release
        int old = atomicAdd(&done[row], 1);            // device-scope
        winner_sh = (old == SLICES - 1);
    }
    __syncthreads();
    if (!winner_sh) return;                            // block-uniform exit
    __threadfence();                                   // acquire side

    // ---------------- select phase (winner block only) ----------------
    const int k_in = *topk_p;
    if (tid < SLICES) segc[tid] = scnt[row * SLICES + tid];
    if (tid == 0) { hi_cnt = 0; cpos = 0; scount = 0; }
    __syncthreads();
    if (tid == 0) {
        int acc = 0, bad = 0;
        for (int s = 0; s < SLICES; ++s) {
            segoff[s] = acc;
            int c = segc[s];
            if (c > SEGCAP) bad = 1;
            acc += min(c, SEGCAP);
        }
        segoff[SLICES] = acc;
        bad_sh = bad;
    }
    __syncthreads();

    const int M_all = segoff[SLICES];
    int M;
    if (!bad_sh && M_all >= k_in && M_all <= MSORT) {
        // gather: 16 threads per segment (one global-latency round, parallel)
        {
            const int s  = tid >> 4;
            const int j0 = tid & 15;
            const int off = segoff[s];
            const int c   = segoff[s + 1] - off;
            const float* cyr = cy + ((size_t)row * SLICES + s) * SEGCAP;
            const int*   cir = ci + ((size_t)row * SLICES + s) * SEGCAP;
            int myhi = 0;
            for (int j = j0; j < c; j += 16) {
                float x = cyr[j] / TEMP;
                gv[off + j] = x;
                gi[off + j] = cir[j];
                myhi += (x >= XTH2);
            }
            if (myhi) atomicAdd(&hi_cnt, myhi);
        }
        __syncthreads();
        // two-tier compact (order irrelevant; sort is a total order)
        const float thr = (hi_cnt >= k_in) ? XTH2 : -1e38f;
        for (int t = tid; t < M_all; t += 256) {
            float x = gv[t];
            if (x >= thr) {
                int p = atomicAdd(&cpos, 1);
                cv[p] = x; cidx[p] = gi[t];
            }
        }
        __syncthreads();
        M = cpos;
    } else {
        // exact fallback: kth value via binary search on float key bits
        unsigned lo = 0;
        for (int bit = 31; bit >= 0; --bit) {
            unsigned t = lo | (1u << bit);
            int local = 0;
            for (int i = tid; i < V; i += 256) local += (fkey(rowp[i]) >= t);
            if (tid == 0) cnt_sh = 0;
            __syncthreads();
            atomicAdd(&cnt_sh, local);
            __syncthreads();
            if (cnt_sh >= k_in) lo = t;
            __syncthreads();
        }
        for (int i = tid; i < V; i += 256) {
            float y = rowp[i];
            if (fkey(y) >= lo) {
                int p = atomicAdd(&scount, 1);
                if (p < MSORT) { cv[p] = y / TEMP; cidx[p] = i; }
            }
        }
        __syncthreads();
        M = min(scount, MSORT);
    }
    if (tid == 0) M_sh = M;
    __syncthreads();
    M = M_sh;

    // pad to multiple of 4 with sentinels (branch-free unrolled inner loop)
    const int Mpad = (M + 3) & ~3;
    for (int t = M + tid; t < Mpad; t += 256) { cv[t] = -1e38f; cidx[t] = 0x7fffffff; }
    __syncthreads();

    // rank sort: x desc, tie idx asc (== argsort(-x)); writes into gv/gi
    for (int t = tid; t < M; t += 256) {
        const float v = cv[t]; const int ix = cidx[t];
        int r = 0;
        for (int j = 0; j < Mpad; j += 4) {
            float v0 = cv[j],     v1 = cv[j + 1];
            float v2 = cv[j + 2], v3 = cv[j + 3];
            int   i0 = cidx[j],     i1 = cidx[j + 1];
            int   i2 = cidx[j + 2], i3 = cidx[j + 3];
            r += (v0 > v || (v0 == v && i0 < ix));
            r += (v1 > v || (v1 == v && i1 < ix));
            r += (v2 > v || (v2 == v && i2 < ix));
            r += (v3 > v || (v3 == v && i3 < ix));
        }
        gv[r] = v; gi[r] = ix;   // gv/gi now hold sorted (ssv/ssi)
    }
    __syncthreads();

    const float mm = (M > 0) ? gv[0] : 0.0f;
    for (int t = tid; t < M; t += 256) cv[t] = expf(gv[t] - mm);  // cv now se
    __syncthreads();

    // serial tiny tail: top-k ties, softmax, top-p prefix cut (fp32 exact)
    if (tid == 0) {
        int L = 0;
        if (M > 0) {
            int kk = k_in; if (kk > M) kk = M; if (kk < 1) kk = 1;
            float kth = gv[kk - 1];
            int Kp = kk;
            while (Kp < M && gv[Kp] == kth) ++Kp;    // keep ties with kth
            float sum1 = 0.0f;
            for (int i = 0; i < Kp; ++i) sum1 += cv[i];
            float cdf = 0.0f;
            for (int i = 0; i < Kp; ++i) {
                if (i > 0 && cdf > TOPP) break;      // remove iff cdf[i-1] > p
                L = i + 1;
                cdf += cv[i] / sum1;
            }
            float sum2 = 0.0f;
            for (int i = 0; i < L; ++i) sum2 += cv[i];
            sum2_sh = sum2;
        } else {
            sum2_sh = 1.0f;
        }
        L_sh = L;
    }
    __syncthreads();
    const int L = L_sh;
    const float sum2 = sum2_sh;

    // reorder kept entries by vocab index; cidx becomes sidx2
    if (tid < L) {
        int ix = gi[tid];
        int r = 0;
        for (int j = 0; j < L; ++j) r += (gi[j] < ix);
        cidx[r] = ix;
        sq[r] = cv[tid] / sum2;
    }
    __syncthreads();

    // inverse-CDF sample: count(csum <= u) = first idx with cum > u
    if (tid == 0) {
        float uu = uvec[row];
        float cum = 0.0f;
        int ans = V;                      // u >= total -> count is V
        for (int i = 0; i < L; ++i) {
            cum += sq[i];
            if (cum > uu) { ans = cidx[i]; break; }
        }
        out[row] = ans;
    }
}

extern "C" void kernel_launch(void* const* d_in, const int* in_sizes, int n_in,
                              void* d_out, int out_size, void* d_ws, size_t ws_size,
                              hipStream_t stream) {
    const float* logits = (const float*)d_in[0];
    const float* u      = (const float*)d_in[1];
    const int*   topk   = (const int*)d_in[2];
    int*         out    = (int*)d_out;

    const int B = out_size;              // 128 rows
    const int V = in_sizes[0] / B;       // 128000

    // ws layout: done[B] | scnt[B*SLICES] | cy[B*SLICES*SEGCAP f32] | ci[same i32]
    int*   done = (int*)d_ws;
    int*   scnt = done + B;
    float* cy   = (float*)(scnt + (size_t)B * SLICES);
    int*   ci   = (int*)(cy + (size_t)B * SLICES * SEGCAP);

    hipMemsetAsync(done, 0, (size_t)B * sizeof(int), stream);
    fused_sampler_kernel<<<B * SLICES, 256, 0, stream>>>(
        logits, u, topk, done, scnt, cy, ci, out, V);
}

// Round 6
// 103.753 us; speedup vs baseline: 1.8991x; 1.8991x over previous
//
#include <hip/hip_runtime.h>
#include <math.h>

// Sampler: temperature 0.8, top-k (k=50 input), top-p 0.9, inverse-CDF
// multinomial. B=128 rows, V=128000, fp32 logits -> int32 ids.
//
// R6: ONE kernel, ONE block per row, 1024 threads. Zero cross-block
// communication (R5's 2048 device-scope release fences == 2048 L2
// writeback-invalidates were the regression; R2's global atomics before
// that). Everything stays in-block:
//  - scan: 8 float4 loads in flight per thread (4 batches over the row);
//    candidates (y >= 11.2, i.e. x >= 14, ~327/row) pushed into LDS via
//    LDS atomics. No histogram.
//  - two-tier filter: if #{x >= 16} >= k (expected ~88), sort only those.
//    Exact: kept set is a superset of top-k plus all kth ties.
//  - rank sort (x desc, idx asc == jnp.argsort(-x) stability), 1 elem/thread,
//    inner loop unrolled x4 over -inf-padded list.
//  - serial fp32 softmax / top-p / inverse-CDF tail: byte-identical to the
//    absmax-0 R1-R5 code.
//  - fallback (candidate overflow or < k): exact kth via 32-step binary
//    search on float key bits + rescan. Never fires on this data.
// LDS ~20.6 KB, no workspace, no memset, single launch.

#define MSORT 1024

__device__ __forceinline__ unsigned fkey(float y) {
    unsigned b = __float_as_uint(y);
    return (b & 0x80000000u) ? ~b : (b | 0x80000000u);  // y asc -> key asc
}

__global__ __launch_bounds__(1024)
void sampler_kernel(const float* __restrict__ logits,
                    const float* __restrict__ uvec,
                    const int* __restrict__ topk_p,
                    int* __restrict__ out, int V)
{
    constexpr float YTH  = 11.2f;   // candidate threshold in y-space (x = 14)
    constexpr float TEMP = 0.8f;
    constexpr float TOPP = 0.9f;
    constexpr float XTH2 = 16.0f;   // two-tier threshold in x-space (y = 12.8)

    __shared__ float gv[MSORT];     // candidates x  -> later sorted values
    __shared__ int   gi[MSORT];     // candidate idx -> later sorted indices
    __shared__ float cv[MSORT];     // compacted x   -> later se = exp(x-max)
    __shared__ int   cidx[MSORT];   // compacted idx -> later vocab-order idx
    __shared__ float sq[MSORT];     // final probs, vocab order
    __shared__ int   lcnt, hi_cnt, cpos, scount, cnt_sh, L_sh, M_sh;
    __shared__ float sum2_sh;

    const int tid = threadIdx.x;
    const int row = blockIdx.x;
    const int nth = blockDim.x;     // 1024

    if (tid == 0) { lcnt = 0; hi_cnt = 0; cpos = 0; scount = 0; }
    __syncthreads();

    const float* rowp = logits + (size_t)row * (size_t)V;
    const float4* rp4 = (const float4*)rowp;
    const int n4 = V >> 2;

    // ---------------- scan: 8 float4 loads in flight per thread ----------------
    for (int cb = 0; cb < n4; cb += 8 * 1024) {
        float4 vals[8];
        const int base = cb + tid;
#pragma unroll
        for (int j = 0; j < 8; ++j) {
            int i = base + j * 1024;
            vals[j] = (i < n4) ? rp4[i]
                               : make_float4(-1e30f, -1e30f, -1e30f, -1e30f);
        }
#pragma unroll
        for (int j = 0; j < 8; ++j) {
            int i = base + j * 1024;
            float ys[4] = {vals[j].x, vals[j].y, vals[j].z, vals[j].w};
#pragma unroll
            for (int c = 0; c < 4; ++c) {
                if (ys[c] >= YTH) {
                    int p = atomicAdd(&lcnt, 1);          // LDS atomic
                    if (p < MSORT) { gv[p] = ys[c] / TEMP; gi[p] = i * 4 + c; }
                }
            }
        }
    }
    for (int i = (n4 << 2) + tid; i < V; i += nth) {      // tail if V % 4 != 0
        float y = rowp[i];
        if (y >= YTH) {
            int p = atomicAdd(&lcnt, 1);
            if (p < MSORT) { gv[p] = y / TEMP; gi[p] = i; }
        }
    }
    __syncthreads();

    const int k_in = *topk_p;
    const int M_all = min(lcnt, MSORT);
    int M;

    if (lcnt <= MSORT && M_all >= k_in) {
        // ---- two-tier: count x >= XTH2 (one candidate per thread) ----
        {
            int pred = (tid < M_all) && (gv[tid] >= XTH2);
            unsigned long long bm = __ballot(pred);
            if ((tid & 63) == 0 && bm) atomicAdd(&hi_cnt, __popcll(bm));
        }
        __syncthreads();
        // ---- compact (order irrelevant; rank sort is a total order) ----
        const float thr = (hi_cnt >= k_in) ? XTH2 : -1e38f;
        if (tid < M_all && gv[tid] >= thr) {
            int p = atomicAdd(&cpos, 1);
            cv[p] = gv[tid]; cidx[p] = gi[tid];
        }
        __syncthreads();
        M = cpos;
    } else {
        // ---- exact fallback: kth value via binary search on float key bits ----
        unsigned lo = 0;
        for (int bit = 31; bit >= 0; --bit) {
            unsigned t = lo | (1u << bit);
            int local = 0;
            for (int i = tid; i < V; i += nth) local += (fkey(rowp[i]) >= t);
            if (tid == 0) cnt_sh = 0;
            __syncthreads();
            atomicAdd(&cnt_sh, local);
            __syncthreads();
            if (cnt_sh >= k_in) lo = t;
            __syncthreads();
        }
        for (int i = tid; i < V; i += nth) {
            float y = rowp[i];
            if (fkey(y) >= lo) {
                int p = atomicAdd(&scount, 1);
                if (p < MSORT) { cv[p] = y / TEMP; cidx[p] = i; }
            }
        }
        __syncthreads();
        M = min(scount, MSORT);
    }
    if (tid == 0) M_sh = M;
    __syncthreads();
    M = M_sh;

    // ---- pad to multiple of 4 with sentinels (branch-free unrolled loop) ----
    const int Mpad = (M + 3) & ~3;
    for (int t = M + tid; t < Mpad; t += nth) { cv[t] = -1e38f; cidx[t] = 0x7fffffff; }
    __syncthreads();

    // ---- rank sort: x desc, tie idx asc (== argsort(-x)); 1 elem/thread ----
    if (tid < M) {
        const float v = cv[tid]; const int ix = cidx[tid];
        int r = 0;
        for (int j = 0; j < Mpad; j += 4) {
            float v0 = cv[j],     v1 = cv[j + 1];
            float v2 = cv[j + 2], v3 = cv[j + 3];
            int   i0 = cidx[j],     i1 = cidx[j + 1];
            int   i2 = cidx[j + 2], i3 = cidx[j + 3];
            r += (v0 > v || (v0 == v && i0 < ix));
            r += (v1 > v || (v1 == v && i1 < ix));
            r += (v2 > v || (v2 == v && i2 < ix));
            r += (v3 > v || (v3 == v && i3 < ix));
        }
        gv[r] = v; gi[r] = ix;      // gv/gi now hold the sorted list
    }
    __syncthreads();

    const float mm = (M > 0) ? gv[0] : 0.0f;
    if (tid < M) cv[tid] = expf(gv[tid] - mm);            // cv now se
    __syncthreads();

    // ---- serial tail: top-k ties, softmax, top-p prefix cut (fp32 exact) ----
    if (tid == 0) {
        int L = 0;
        if (M > 0) {
            int kk = k_in; if (kk > M) kk = M; if (kk < 1) kk = 1;
            float kth = gv[kk - 1];
            int Kp = kk;
            while (Kp < M && gv[Kp] == kth) ++Kp;         // keep ties with kth
            float sum1 = 0.0f;
            for (int i = 0; i < Kp; ++i) sum1 += cv[i];
            float cdf = 0.0f;
            for (int i = 0; i < Kp; ++i) {
                if (i > 0 && cdf > TOPP) break;           // remove iff cdf[i-1] > p
                L = i + 1;
                cdf += cv[i] / sum1;
            }
            float sum2 = 0.0f;
            for (int i = 0; i < L; ++i) sum2 += cv[i];
            sum2_sh = sum2;
        } else {
            sum2_sh = 1.0f;
        }
        L_sh = L;
    }
    __syncthreads();
    const int L = L_sh;
    const float sum2 = sum2_sh;

    // ---- reorder kept entries by vocab index; cidx becomes vocab-order ----
    if (tid < L) {
        int ix = gi[tid];
        int r = 0;
        for (int j = 0; j < L; ++j) r += (gi[j] < ix);
        cidx[r] = ix;
        sq[r] = cv[tid] / sum2;
    }
    __syncthreads();

    // ---- inverse-CDF sample: count(csum <= u) = first idx with cum > u ----
    if (tid == 0) {
        float uu = uvec[row];
        float cum = 0.0f;
        int ans = V;                     // u >= total -> count is V
        for (int i = 0; i < L; ++i) {
            cum += sq[i];
            if (cum > uu) { ans = cidx[i]; break; }
        }
        out[row] = ans;
    }
}

extern "C" void kernel_launch(void* const* d_in, const int* in_sizes, int n_in,
                              void* d_out, int out_size, void* d_ws, size_t ws_size,
                              hipStream_t stream) {
    const float* logits = (const float*)d_in[0];
    const float* u      = (const float*)d_in[1];
    const int*   topk   = (const int*)d_in[2];
    int*         out    = (int*)d_out;

    const int B = out_size;              // 128 rows
    const int V = in_sizes[0] / B;       // 128000

    sampler_kernel<<<B, 1024, 0, stream>>>(logits, u, topk, out, V);
}